// Round 4
// baseline (708.349 us; speedup 1.0000x reference)
//
#include <hip/hip_runtime.h>
#include <math.h>

// Problem constants
#define Bx 4
#define Tt 8192
#define Nn (Bx * Tt)        // 32768 tokens
#define Dd 512
#define Ee 8
#define Kk 2
#define Ff 2048
#define Cc 5120             // ceil(1.25 * N / E)
#define NK (Nn * Kk)        // 65536 routing slots

typedef unsigned short ushort_t;
typedef __attribute__((ext_vector_type(8))) short bf16x8;   // MFMA A/B frag (4 VGPR)
typedef __attribute__((ext_vector_type(4))) float f32x4;    // MFMA C/D frag

__device__ __forceinline__ float gelu_exact(float v) {
    return 0.5f * v * (1.0f + erff(v * 0.70710678118654752440f));
}

// fp32 -> bf16 RNE
__device__ __forceinline__ ushort_t f2bf(float f) {
    union { float f; unsigned u; } v; v.f = f;
    unsigned r = v.u + 0x7fffu + ((v.u >> 16) & 1u);
    return (ushort_t)(r >> 16);
}

// async global->LDS, 16B per lane. LDS dest is wave-uniform base; HW adds lane*16.
__device__ __forceinline__ void gload_lds16(const ushort_t* g, short* l) {
    __builtin_amdgcn_global_load_lds(
        (const __attribute__((address_space(1))) unsigned int*)g,
        (__attribute__((address_space(3))) unsigned int*)l, 16, 0, 0);
}

// ---------------------------------------------------------------------------
// Kernel 1: gating — logits, softmax, top-2, normalized weights (verified r2)
// ---------------------------------------------------------------------------
__global__ __launch_bounds__(256) void moe_gate_kernel(
    const float* __restrict__ x, const float* __restrict__ gate_w,
    int* __restrict__ flat_e, float* __restrict__ wArr) {
    __shared__ float gw[Ee * Dd];   // 16 KB
    int tid = threadIdx.x;
    for (int i = tid; i < 1024; i += 256)
        ((float4*)gw)[i] = ((const float4*)gate_w)[i];
    __syncthreads();

    int wave = tid >> 6, lane = tid & 63;
    int token = blockIdx.x * 4 + wave;

    const float4* xr = (const float4*)(x + (size_t)token * Dd);
    float4 xa = xr[lane];
    float4 xb = xr[lane + 64];

    float acc[Ee];
#pragma unroll
    for (int e = 0; e < Ee; e++) {
        const float4* g = (const float4*)(gw + e * Dd);
        float4 ga = g[lane], gb = g[lane + 64];
        acc[e] = xa.x * ga.x + xa.y * ga.y + xa.z * ga.z + xa.w * ga.w +
                 xb.x * gb.x + xb.y * gb.y + xb.z * gb.z + xb.w * gb.w;
    }
#pragma unroll
    for (int off = 32; off >= 1; off >>= 1) {
#pragma unroll
        for (int e = 0; e < Ee; e++) acc[e] += __shfl_xor(acc[e], off, 64);
    }

    if (lane == 0) {
        float m = acc[0];
#pragma unroll
        for (int e = 1; e < Ee; e++) m = fmaxf(m, acc[e]);
        float p[Ee], s = 0.f;
#pragma unroll
        for (int e = 0; e < Ee; e++) { p[e] = expf(acc[e] - m); s += p[e]; }
        int i0 = 0;
#pragma unroll
        for (int e = 1; e < Ee; e++) if (p[e] > p[i0]) i0 = e;
        int i1 = (i0 == 0) ? 1 : 0;
#pragma unroll
        for (int e = 0; e < Ee; e++) if (e != i0 && p[e] > p[i1]) i1 = e;
        float v0 = p[i0] / s, v1 = p[i1] / s;
        float inv = 1.f / (v0 + v1);
        flat_e[token * 2 + 0] = i0;
        flat_e[token * 2 + 1] = i1;
        wArr[token * 2 + 0] = v0 * inv;
        wArr[token * 2 + 1] = v1 * inv;
    }
}

// ---------------------------------------------------------------------------
// Kernels 2-4: routing (verified r2): histogram -> scan -> ordered scatter
// ---------------------------------------------------------------------------
__global__ __launch_bounds__(256) void moe_hist_kernel(
    const int* __restrict__ flat_e, int* __restrict__ blockCounts) {
    __shared__ int cnt[Ee];
    int tid = threadIdx.x;
    if (tid < Ee) cnt[tid] = 0;
    __syncthreads();
    int e = flat_e[blockIdx.x * 256 + tid];
    atomicAdd(&cnt[e], 1);
    __syncthreads();
    if (tid < Ee) blockCounts[blockIdx.x * Ee + tid] = cnt[tid];
}

__global__ void moe_scan_kernel(const int* __restrict__ blockCounts,
                                int* __restrict__ blockOffsets,
                                int* __restrict__ counts) {
    int e = threadIdx.x;
    if (e >= Ee) return;
    int run = 0;
    for (int b = 0; b < 256; b++) {
        blockOffsets[b * Ee + e] = run;
        run += blockCounts[b * Ee + e];
    }
    counts[e] = min(run, Cc);
}

__global__ __launch_bounds__(256) void moe_scatter_kernel(
    const int* __restrict__ flat_e, const float* __restrict__ wArr,
    const int* __restrict__ blockOffsets,
    int* __restrict__ srcOf, float* __restrict__ wSlot) {
    __shared__ int waveCnt[4][Ee];
    int tid = threadIdx.x;
    int i = blockIdx.x * 256 + tid;
    int e = flat_e[i];
    int wv = tid >> 6, lane = tid & 63;
    unsigned long long ltmask = (1ull << lane) - 1ull;
    int myrank = 0;
#pragma unroll
    for (int ee = 0; ee < Ee; ee++) {
        unsigned long long m = __ballot(e == ee);
        if (e == ee) myrank = __popcll(m & ltmask);
        if (lane == 0) waveCnt[wv][ee] = __popcll(m);
    }
    __syncthreads();
    int base = blockOffsets[blockIdx.x * Ee + e];
    for (int w = 0; w < wv; w++) base += waveCnt[w][e];
    int pos = base + myrank;
    if (pos < Cc) {
        srcOf[e * Cc + pos] = i >> 1;   // token id
        wSlot[e * Cc + pos] = wArr[i];
    }
}

// ---------------------------------------------------------------------------
// Kernel 5: fp32 [E][R][Cn] -> bf16 [E][Cn][R] transpose (weights to B^T form)
// ---------------------------------------------------------------------------
__global__ __launch_bounds__(256) void moe_transpose_kernel(
    const float* __restrict__ in, ushort_t* __restrict__ out, int R, int Cn) {
    __shared__ float t[32][33];
    int ez = blockIdx.z;
    const float* ine = in + (size_t)ez * R * Cn;
    ushort_t* oute = out + (size_t)ez * R * Cn;
    int tx = threadIdx.x & 31, ty = threadIdx.x >> 5;   // 32 x 8
    int r0 = blockIdx.y * 32, c0 = blockIdx.x * 32;
#pragma unroll
    for (int j = 0; j < 4; j++)
        t[ty + j * 8][tx] = ine[(size_t)(r0 + ty + j * 8) * Cn + c0 + tx];
    __syncthreads();
#pragma unroll
    for (int j = 0; j < 4; j++)
        oute[(size_t)(c0 + ty + j * 8) * R + r0 + tx] = f2bf(t[tx][ty + j * 8]);
}

// ---------------------------------------------------------------------------
// Kernel 6: gather + fp32->bf16: xg[slot][d] = bf16(x[srcOf[slot]][d]) or 0
// ---------------------------------------------------------------------------
__global__ __launch_bounds__(256) void moe_gather_kernel(
    const float* __restrict__ x, const int* __restrict__ srcOf,
    const int* __restrict__ counts, int chunk0, ushort_t* __restrict__ xg) {
    int tid = threadIdx.x, wave = tid >> 6, lane = tid & 63;
    int sl = blockIdx.x * 4 + wave;      // local slot within chunk
    int le = sl / Cc, c = sl - le * Cc;
    int e = chunk0 + le;
    int cnt = counts[e];
    ushort_t* dst = xg + (size_t)sl * Dd + lane * 8;
    uint4 o;
    if (c < cnt) {
        int src = srcOf[e * Cc + c];
        const float4* xr = (const float4*)(x + (size_t)src * Dd + lane * 8);
        float4 v0 = xr[0], v1 = xr[1];
        o.x = (unsigned)f2bf(v0.x) | ((unsigned)f2bf(v0.y) << 16);
        o.y = (unsigned)f2bf(v0.z) | ((unsigned)f2bf(v0.w) << 16);
        o.z = (unsigned)f2bf(v1.x) | ((unsigned)f2bf(v1.y) << 16);
        o.w = (unsigned)f2bf(v1.z) | ((unsigned)f2bf(v1.w) << 16);
    } else {
        o = make_uint4(0, 0, 0, 0);
    }
    *(uint4*)dst = o;
}

// ---------------------------------------------------------------------------
// MFMA GEMM, 2-phase counted-vmcnt double-buffer (T3-minimum recipe):
//   prologue STAGE(buf0,t0) ; loop { STAGE(buf^1,t+1); vmcnt(4); s_barrier;
//   ds_read frags; MFMA; s_barrier; }
// vmcnt(4) keeps next tile's 4 loads in flight across both barriers.
// Raw s_barrier (NOT __syncthreads — that drains vmcnt(0)).
// LDS [buf(2)][kslot(4)][row(128)][8] -> linear gload dest, conflict-free reads
// (SQ_LDS_BANK_CONFLICT measured 0 in r3).
// ---------------------------------------------------------------------------

#define GSTAGE(gA, gB, Al, Bl, buf, t, wbase)                                  \
    do {                                                                       \
        int _k = (t) * 32;                                                     \
        gload_lds16((gA) + _k,      &(Al)[(buf) * 4096 + (wbase)]);            \
        gload_lds16((gA) + _k + 16, &(Al)[(buf) * 4096 + 2048 + (wbase)]);     \
        gload_lds16((gB) + _k,      &(Bl)[(buf) * 4096 + (wbase)]);            \
        gload_lds16((gB) + _k + 16, &(Bl)[(buf) * 4096 + 2048 + (wbase)]);     \
    } while (0)

// Kernel 7: h = gelu(xg @ w1t^T + b1)  (per expert; M=Cc, N=Ff, K=Dd)
__global__ __launch_bounds__(256) void moe_mfma_gemm1(
    const ushort_t* __restrict__ xg, const ushort_t* __restrict__ w1t,
    const float* __restrict__ b1, int chunk0, ushort_t* __restrict__ hbuf) {
    int le = blockIdx.z, e = chunk0 + le;
    const ushort_t* A = xg + (size_t)le * Cc * Dd;
    const ushort_t* Bt = w1t + (size_t)e * Ff * Dd;
    const float* bias = b1 + (size_t)e * Ff;
    ushort_t* h = hbuf + (size_t)le * Cc * Ff;

    __shared__ short Al[2 * 4096];   // 16 KB (double-buffered)
    __shared__ short Bl[2 * 4096];   // 16 KB

    int tid = threadIdx.x;
    int lane = tid & 63, wave = tid >> 6;
    int wr = wave >> 1, wc = wave & 1;
    int m0 = blockIdx.y * 128;
    int n0 = blockIdx.x * 128;
    int kslot = lane >> 4, lr = lane & 15;
    int aoff = (kslot * 128 + wr * 64 + lr) * 8;
    int boff = (kslot * 128 + wc * 64 + lr) * 8;
    int wbase = (tid & 192) * 8;        // wave-uniform LDS chunk base (elems)
    int row = tid & 127, ks0 = tid >> 7;

    const ushort_t* gA = A + (size_t)(m0 + row) * Dd + ks0 * 8;
    const ushort_t* gB = Bt + (size_t)(n0 + row) * Dd + ks0 * 8;

    f32x4 acc[4][4] = {};
    const int NT = Dd / 32;             // 16

    GSTAGE(gA, gB, Al, Bl, 0, 0, wbase);
    for (int t = 0; t < NT; ++t) {
        int cur = t & 1;
        if (t + 1 < NT) {
            GSTAGE(gA, gB, Al, Bl, cur ^ 1, t + 1, wbase);
            asm volatile("s_waitcnt vmcnt(4)" ::: "memory");
        } else {
            asm volatile("s_waitcnt vmcnt(0)" ::: "memory");
        }
        __builtin_amdgcn_s_barrier();
        asm volatile("" ::: "memory");
        bf16x8 a[4], b[4];
        int ab = cur * 4096 + aoff, bb = cur * 4096 + boff;
#pragma unroll
        for (int m = 0; m < 4; ++m) a[m] = *(const bf16x8*)&Al[ab + m * 128];
#pragma unroll
        for (int n = 0; n < 4; ++n) b[n] = *(const bf16x8*)&Bl[bb + n * 128];
#pragma unroll
        for (int m = 0; m < 4; ++m)
#pragma unroll
            for (int n = 0; n < 4; ++n)
                acc[m][n] = __builtin_amdgcn_mfma_f32_16x16x32_bf16(
                    a[m], b[n], acc[m][n], 0, 0, 0);
        asm volatile("" ::: "memory");
        __builtin_amdgcn_s_barrier();
    }

    float bv[4];
#pragma unroll
    for (int n = 0; n < 4; ++n) bv[n] = bias[n0 + wc * 64 + n * 16 + lr];
#pragma unroll
    for (int m = 0; m < 4; ++m) {
#pragma unroll
        for (int r = 0; r < 4; ++r) {
            int orow = m0 + wr * 64 + m * 16 + kslot * 4 + r;
            size_t base = (size_t)orow * Ff + n0 + wc * 64 + lr;
#pragma unroll
            for (int n = 0; n < 4; ++n)
                h[base + n * 16] = f2bf(gelu_exact(acc[m][n][r] + bv[n]));
        }
    }
}

// Kernel 8: out[token] += w * (h @ w2t^T + b2)  (per expert; M=Cc, N=Dd, K=Ff)
// Split-K over blockIdx.z (free: epilogue is atomicAdd, bias only on split 0).
__global__ __launch_bounds__(256) void moe_mfma_gemm2(
    const ushort_t* __restrict__ hbuf, const ushort_t* __restrict__ w2t,
    const float* __restrict__ b2, const int* __restrict__ srcOf,
    const float* __restrict__ wSlot, const int* __restrict__ counts,
    int chunk0, float* __restrict__ out) {
    int z = blockIdx.z;
    int le = z >> 1, ksp = z & 1;       // expert-in-chunk, K-split half
    int e = chunk0 + le;
    const int KH = Ff / 2;              // 1024 per split
    const ushort_t* A = hbuf + (size_t)le * Cc * Ff + (size_t)ksp * KH;
    const ushort_t* Bt = w2t + (size_t)e * Dd * Ff + (size_t)ksp * KH;
    const float* bias = b2 + (size_t)e * Dd;
    const int* srcE = srcOf + (size_t)e * Cc;
    const float* wE = wSlot + (size_t)e * Cc;
    int count = counts[e];

    __shared__ short Al[2 * 4096];
    __shared__ short Bl[2 * 4096];

    int tid = threadIdx.x;
    int lane = tid & 63, wave = tid >> 6;
    int wr = wave >> 1, wc = wave & 1;
    int m0 = blockIdx.y * 128;
    int n0 = blockIdx.x * 128;
    int kslot = lane >> 4, lr = lane & 15;
    int aoff = (kslot * 128 + wr * 64 + lr) * 8;
    int boff = (kslot * 128 + wc * 64 + lr) * 8;
    int wbase = (tid & 192) * 8;
    int row = tid & 127, ks0 = tid >> 7;

    const ushort_t* gA = A + (size_t)(m0 + row) * Ff + ks0 * 8;
    const ushort_t* gB = Bt + (size_t)(n0 + row) * Ff + ks0 * 8;

    f32x4 acc[4][4] = {};
    const int NT = KH / 32;             // 32

    GSTAGE(gA, gB, Al, Bl, 0, 0, wbase);
    for (int t = 0; t < NT; ++t) {
        int cur = t & 1;
        if (t + 1 < NT) {
            GSTAGE(gA, gB, Al, Bl, cur ^ 1, t + 1, wbase);
            asm volatile("s_waitcnt vmcnt(4)" ::: "memory");
        } else {
            asm volatile("s_waitcnt vmcnt(0)" ::: "memory");
        }
        __builtin_amdgcn_s_barrier();
        asm volatile("" ::: "memory");
        bf16x8 a[4], b[4];
        int ab = cur * 4096 + aoff, bb = cur * 4096 + boff;
#pragma unroll
        for (int m = 0; m < 4; ++m) a[m] = *(const bf16x8*)&Al[ab + m * 128];
#pragma unroll
        for (int n = 0; n < 4; ++n) b[n] = *(const bf16x8*)&Bl[bb + n * 128];
#pragma unroll
        for (int m = 0; m < 4; ++m)
#pragma unroll
            for (int n = 0; n < 4; ++n)
                acc[m][n] = __builtin_amdgcn_mfma_f32_16x16x32_bf16(
                    a[m], b[n], acc[m][n], 0, 0, 0);
        asm volatile("" ::: "memory");
        __builtin_amdgcn_s_barrier();
    }

    float bv[4];
#pragma unroll
    for (int n = 0; n < 4; ++n)
        bv[n] = (ksp == 0) ? bias[n0 + wc * 64 + n * 16 + lr] : 0.f;
#pragma unroll
    for (int m = 0; m < 4; ++m) {
#pragma unroll
        for (int r = 0; r < 4; ++r) {
            int orow = m0 + wr * 64 + m * 16 + kslot * 4 + r;
            if (orow < count) {
                int token = srcE[orow];
                float wgt = wE[orow];
                float* op = out + (size_t)token * Dd + n0 + wc * 64 + lr;
#pragma unroll
                for (int n = 0; n < 4; ++n)
                    atomicAdd(&op[n * 16], wgt * (acc[m][n][r] + bv[n]));
            }
        }
    }
}

// ---------------------------------------------------------------------------
extern "C" void kernel_launch(void* const* d_in, const int* in_sizes, int n_in,
                              void* d_out, int out_size, void* d_ws, size_t ws_size,
                              hipStream_t stream) {
    const float* x      = (const float*)d_in[0];
    const float* gate_w = (const float*)d_in[1];
    const float* w1     = (const float*)d_in[2];
    const float* b1     = (const float*)d_in[3];
    const float* w2     = (const float*)d_in[4];
    const float* b2     = (const float*)d_in[5];
    float* out = (float*)d_out;

    char* p = (char*)d_ws;
    int*      flat_e       = (int*)p;       p += (size_t)NK * 4;
    float*    wArr         = (float*)p;     p += (size_t)NK * 4;
    int*      blockCounts  = (int*)p;       p += 256 * Ee * 4;
    int*      blockOffsets = (int*)p;       p += 256 * Ee * 4;
    int*      counts       = (int*)p;       p += 64 * 4;
    int*      srcOf        = (int*)p;       p += (size_t)Ee * Cc * 4;
    float*    wSlot        = (float*)p;     p += (size_t)Ee * Cc * 4;
    p = (char*)(((size_t)p + 255) & ~(size_t)255);
    ushort_t* w1t          = (ushort_t*)p;  p += (size_t)Ee * Dd * Ff * 2;
    ushort_t* w2t          = (ushort_t*)p;  p += (size_t)Ee * Ff * Dd * 2;
    size_t fixedEnd = (size_t)(p - (char*)d_ws);
    size_t avail = (ws_size > fixedEnd) ? ws_size - fixedEnd : 0;

    // per-expert chunk buffers: xg (Cc x Dd bf16) + h (Cc x Ff bf16)
    size_t perE = (size_t)Cc * Dd * 2 + (size_t)Cc * Ff * 2;
    int P = Ee;
    while (P > 1 && (size_t)P * perE > avail) P >>= 1;
    ushort_t* xg = (ushort_t*)((char*)d_ws + fixedEnd);
    ushort_t* hbuf = xg + (size_t)P * Cc * Dd;

    moe_gate_kernel<<<Nn / 4, 256, 0, stream>>>(x, gate_w, flat_e, wArr);
    moe_hist_kernel<<<NK / 256, 256, 0, stream>>>(flat_e, blockCounts);
    moe_scan_kernel<<<1, 64, 0, stream>>>(blockCounts, blockOffsets, counts);
    moe_scatter_kernel<<<NK / 256, 256, 0, stream>>>(flat_e, wArr, blockOffsets,
                                                     srcOf, wSlot);
    moe_transpose_kernel<<<dim3(Ff / 32, Dd / 32, Ee), 256, 0, stream>>>(
        w1, w1t, Dd, Ff);
    moe_transpose_kernel<<<dim3(Dd / 32, Ff / 32, Ee), 256, 0, stream>>>(
        w2, w2t, Ff, Dd);
    hipMemsetAsync(d_out, 0, (size_t)Nn * Dd * sizeof(float), stream);

    for (int c0 = 0; c0 < Ee; c0 += P) {
        moe_gather_kernel<<<P * Cc / 4, 256, 0, stream>>>(x, srcOf, counts, c0, xg);
        moe_mfma_gemm1<<<dim3(Ff / 128, Cc / 128, P), 256, 0, stream>>>(
            xg, w1t, b1, c0, hbuf);
        moe_mfma_gemm2<<<dim3(Dd / 128, Cc / 128, P * 2), 256, 0, stream>>>(
            hbuf, w2t, b2, srcOf, wSlot, counts, c0, out);
    }
}

// Round 5
// 653.300 us; speedup vs baseline: 1.0843x; 1.0843x over previous
//
#include <hip/hip_runtime.h>
#include <math.h>

// Problem constants
#define Bx 4
#define Tt 8192
#define Nn (Bx * Tt)        // 32768 tokens
#define Dd 512
#define Ee 8
#define Kk 2
#define Ff 2048
#define Cc 5120             // ceil(1.25 * N / E)
#define NK (Nn * Kk)        // 65536 routing slots

typedef unsigned short ushort_t;
typedef __attribute__((ext_vector_type(8))) short bf16x8;   // MFMA A/B frag (4 VGPR)
typedef __attribute__((ext_vector_type(4))) float f32x4;    // MFMA C/D frag

__device__ __forceinline__ float gelu_exact(float v) {
    return 0.5f * v * (1.0f + erff(v * 0.70710678118654752440f));
}

// fp32 -> bf16 RNE
__device__ __forceinline__ ushort_t f2bf(float f) {
    union { float f; unsigned u; } v; v.f = f;
    unsigned r = v.u + 0x7fffu + ((v.u >> 16) & 1u);
    return (ushort_t)(r >> 16);
}

// async global->LDS, 16B per lane. LDS dest is wave-uniform base; HW adds lane*16.
__device__ __forceinline__ void gload_lds16(const ushort_t* g, short* l) {
    __builtin_amdgcn_global_load_lds(
        (const __attribute__((address_space(1))) unsigned int*)g,
        (__attribute__((address_space(3))) unsigned int*)l, 16, 0, 0);
}

// T1 XCD-aware bijective swizzle (orig%8 ~ XCD on MI355X round-robin dispatch).
// Requires nwg % 8 == 0 (all our grids satisfy this). Decode x-innermost so each
// XCD owns a contiguous (z,y,x) chunk -> A-panels shared within one L2.
__device__ __forceinline__ void swz_decode(int gx, int gy, int& x, int& y, int& z) {
    int nwg = gridDim.x * gridDim.y * gridDim.z;
    int orig = blockIdx.x + gridDim.x * (blockIdx.y + gridDim.y * blockIdx.z);
    int cpx = nwg >> 3;
    int id = (orig & 7) * cpx + (orig >> 3);
    x = id % gx; id /= gx;
    y = id % gy; z = id / gy;
}

// ---------------------------------------------------------------------------
// Kernel 1: gating — logits, softmax, top-2, normalized weights (verified r2)
// ---------------------------------------------------------------------------
__global__ __launch_bounds__(256) void moe_gate_kernel(
    const float* __restrict__ x, const float* __restrict__ gate_w,
    int* __restrict__ flat_e, float* __restrict__ wArr) {
    __shared__ float gw[Ee * Dd];   // 16 KB
    int tid = threadIdx.x;
    for (int i = tid; i < 1024; i += 256)
        ((float4*)gw)[i] = ((const float4*)gate_w)[i];
    __syncthreads();

    int wave = tid >> 6, lane = tid & 63;
    int token = blockIdx.x * 4 + wave;

    const float4* xr = (const float4*)(x + (size_t)token * Dd);
    float4 xa = xr[lane];
    float4 xb = xr[lane + 64];

    float acc[Ee];
#pragma unroll
    for (int e = 0; e < Ee; e++) {
        const float4* g = (const float4*)(gw + e * Dd);
        float4 ga = g[lane], gb = g[lane + 64];
        acc[e] = xa.x * ga.x + xa.y * ga.y + xa.z * ga.z + xa.w * ga.w +
                 xb.x * gb.x + xb.y * gb.y + xb.z * gb.z + xb.w * gb.w;
    }
#pragma unroll
    for (int off = 32; off >= 1; off >>= 1) {
#pragma unroll
        for (int e = 0; e < Ee; e++) acc[e] += __shfl_xor(acc[e], off, 64);
    }

    if (lane == 0) {
        float m = acc[0];
#pragma unroll
        for (int e = 1; e < Ee; e++) m = fmaxf(m, acc[e]);
        float p[Ee], s = 0.f;
#pragma unroll
        for (int e = 0; e < Ee; e++) { p[e] = expf(acc[e] - m); s += p[e]; }
        int i0 = 0;
#pragma unroll
        for (int e = 1; e < Ee; e++) if (p[e] > p[i0]) i0 = e;
        int i1 = (i0 == 0) ? 1 : 0;
#pragma unroll
        for (int e = 0; e < Ee; e++) if (e != i0 && p[e] > p[i1]) i1 = e;
        float v0 = p[i0] / s, v1 = p[i1] / s;
        float inv = 1.f / (v0 + v1);
        flat_e[token * 2 + 0] = i0;
        flat_e[token * 2 + 1] = i1;
        wArr[token * 2 + 0] = v0 * inv;
        wArr[token * 2 + 1] = v1 * inv;
    }
}

// ---------------------------------------------------------------------------
// Kernels 2-4: routing (verified r2): histogram -> scan -> ordered scatter
// ---------------------------------------------------------------------------
__global__ __launch_bounds__(256) void moe_hist_kernel(
    const int* __restrict__ flat_e, int* __restrict__ blockCounts) {
    __shared__ int cnt[Ee];
    int tid = threadIdx.x;
    if (tid < Ee) cnt[tid] = 0;
    __syncthreads();
    int e = flat_e[blockIdx.x * 256 + tid];
    atomicAdd(&cnt[e], 1);
    __syncthreads();
    if (tid < Ee) blockCounts[blockIdx.x * Ee + tid] = cnt[tid];
}

__global__ void moe_scan_kernel(const int* __restrict__ blockCounts,
                                int* __restrict__ blockOffsets,
                                int* __restrict__ counts) {
    int e = threadIdx.x;
    if (e >= Ee) return;
    int run = 0;
    for (int b = 0; b < 256; b++) {
        blockOffsets[b * Ee + e] = run;
        run += blockCounts[b * Ee + e];
    }
    counts[e] = min(run, Cc);
}

__global__ __launch_bounds__(256) void moe_scatter_kernel(
    const int* __restrict__ flat_e, const float* __restrict__ wArr,
    const int* __restrict__ blockOffsets,
    int* __restrict__ srcOf, float* __restrict__ wSlot) {
    __shared__ int waveCnt[4][Ee];
    int tid = threadIdx.x;
    int i = blockIdx.x * 256 + tid;
    int e = flat_e[i];
    int wv = tid >> 6, lane = tid & 63;
    unsigned long long ltmask = (1ull << lane) - 1ull;
    int myrank = 0;
#pragma unroll
    for (int ee = 0; ee < Ee; ee++) {
        unsigned long long m = __ballot(e == ee);
        if (e == ee) myrank = __popcll(m & ltmask);
        if (lane == 0) waveCnt[wv][ee] = __popcll(m);
    }
    __syncthreads();
    int base = blockOffsets[blockIdx.x * Ee + e];
    for (int w = 0; w < wv; w++) base += waveCnt[w][e];
    int pos = base + myrank;
    if (pos < Cc) {
        srcOf[e * Cc + pos] = i >> 1;   // token id
        wSlot[e * Cc + pos] = wArr[i];
    }
}

// ---------------------------------------------------------------------------
// Kernel 5: fp32 [E][R][Cn] -> bf16 [E][Cn][R] transpose (weights to B^T form)
// ---------------------------------------------------------------------------
__global__ __launch_bounds__(256) void moe_transpose_kernel(
    const float* __restrict__ in, ushort_t* __restrict__ out, int R, int Cn) {
    __shared__ float t[32][33];
    int ez = blockIdx.z;
    const float* ine = in + (size_t)ez * R * Cn;
    ushort_t* oute = out + (size_t)ez * R * Cn;
    int tx = threadIdx.x & 31, ty = threadIdx.x >> 5;   // 32 x 8
    int r0 = blockIdx.y * 32, c0 = blockIdx.x * 32;
#pragma unroll
    for (int j = 0; j < 4; j++)
        t[ty + j * 8][tx] = ine[(size_t)(r0 + ty + j * 8) * Cn + c0 + tx];
    __syncthreads();
#pragma unroll
    for (int j = 0; j < 4; j++)
        oute[(size_t)(c0 + ty + j * 8) * R + r0 + tx] = f2bf(t[tx][ty + j * 8]);
}

// ---------------------------------------------------------------------------
// Kernel 6: gather + fp32->bf16: xg[slot][d] = bf16(x[srcOf[slot]][d]) or 0
// ---------------------------------------------------------------------------
__global__ __launch_bounds__(256) void moe_gather_kernel(
    const float* __restrict__ x, const int* __restrict__ srcOf,
    const int* __restrict__ counts, int chunk0, ushort_t* __restrict__ xg) {
    int tid = threadIdx.x, wave = tid >> 6, lane = tid & 63;
    int sl = blockIdx.x * 4 + wave;      // local slot within chunk
    int le = sl / Cc, c = sl - le * Cc;
    int e = chunk0 + le;
    int cnt = counts[e];
    ushort_t* dst = xg + (size_t)sl * Dd + lane * 8;
    uint4 o;
    if (c < cnt) {
        int src = srcOf[e * Cc + c];
        const float4* xr = (const float4*)(x + (size_t)src * Dd + lane * 8);
        float4 v0 = xr[0], v1 = xr[1];
        o.x = (unsigned)f2bf(v0.x) | ((unsigned)f2bf(v0.y) << 16);
        o.y = (unsigned)f2bf(v0.z) | ((unsigned)f2bf(v0.w) << 16);
        o.z = (unsigned)f2bf(v1.x) | ((unsigned)f2bf(v1.y) << 16);
        o.w = (unsigned)f2bf(v1.z) | ((unsigned)f2bf(v1.w) << 16);
    } else {
        o = make_uint4(0, 0, 0, 0);
    }
    *(uint4*)dst = o;
}

// ---------------------------------------------------------------------------
// MFMA GEMM, 128x128 tile, BK=32, 4 waves, 2-phase counted-vmcnt dbuf
// (measured ~neutral vs drain — kept) + T1 XCD swizzle (new this round).
// LDS [buf(2)][kslot(4)][row(128)][8] -> linear gload dest, conflict-free reads
// (SQ_LDS_BANK_CONFLICT measured 0).
// ---------------------------------------------------------------------------

#define GSTAGE(gA, gB, Al, Bl, buf, t, wbase)                                  \
    do {                                                                       \
        int _k = (t) * 32;                                                     \
        gload_lds16((gA) + _k,      &(Al)[(buf) * 4096 + (wbase)]);            \
        gload_lds16((gA) + _k + 16, &(Al)[(buf) * 4096 + 2048 + (wbase)]);     \
        gload_lds16((gB) + _k,      &(Bl)[(buf) * 4096 + (wbase)]);            \
        gload_lds16((gB) + _k + 16, &(Bl)[(buf) * 4096 + 2048 + (wbase)]);     \
    } while (0)

// Kernel 7: h = gelu(xg @ w1t^T + b1)  (per expert; M=Cc, N=Ff, K=Dd)
__global__ __launch_bounds__(256) void moe_mfma_gemm1(
    const ushort_t* __restrict__ xg, const ushort_t* __restrict__ w1t,
    const float* __restrict__ b1, int chunk0, ushort_t* __restrict__ hbuf) {
    int bx, by, le;
    swz_decode(Ff / 128, Cc / 128, bx, by, le);
    int e = chunk0 + le;
    const ushort_t* A = xg + (size_t)le * Cc * Dd;
    const ushort_t* Bt = w1t + (size_t)e * Ff * Dd;
    const float* bias = b1 + (size_t)e * Ff;
    ushort_t* h = hbuf + (size_t)le * Cc * Ff;

    __shared__ short Al[2 * 4096];   // 16 KB (double-buffered)
    __shared__ short Bl[2 * 4096];   // 16 KB

    int tid = threadIdx.x;
    int lane = tid & 63, wave = tid >> 6;
    int wr = wave >> 1, wc = wave & 1;
    int m0 = by * 128;
    int n0 = bx * 128;
    int kslot = lane >> 4, lr = lane & 15;
    int aoff = (kslot * 128 + wr * 64 + lr) * 8;
    int boff = (kslot * 128 + wc * 64 + lr) * 8;
    int wbase = (tid & 192) * 8;        // wave-uniform LDS chunk base (elems)
    int row = tid & 127, ks0 = tid >> 7;

    const ushort_t* gA = A + (size_t)(m0 + row) * Dd + ks0 * 8;
    const ushort_t* gB = Bt + (size_t)(n0 + row) * Dd + ks0 * 8;

    f32x4 acc[4][4] = {};
    const int NT = Dd / 32;             // 16

    GSTAGE(gA, gB, Al, Bl, 0, 0, wbase);
    for (int t = 0; t < NT; ++t) {
        int cur = t & 1;
        if (t + 1 < NT) {
            GSTAGE(gA, gB, Al, Bl, cur ^ 1, t + 1, wbase);
            asm volatile("s_waitcnt vmcnt(4)" ::: "memory");
        } else {
            asm volatile("s_waitcnt vmcnt(0)" ::: "memory");
        }
        __builtin_amdgcn_s_barrier();
        asm volatile("" ::: "memory");
        bf16x8 a[4], b[4];
        int ab = cur * 4096 + aoff, bb = cur * 4096 + boff;
#pragma unroll
        for (int m = 0; m < 4; ++m) a[m] = *(const bf16x8*)&Al[ab + m * 128];
#pragma unroll
        for (int n = 0; n < 4; ++n) b[n] = *(const bf16x8*)&Bl[bb + n * 128];
#pragma unroll
        for (int m = 0; m < 4; ++m)
#pragma unroll
            for (int n = 0; n < 4; ++n)
                acc[m][n] = __builtin_amdgcn_mfma_f32_16x16x32_bf16(
                    a[m], b[n], acc[m][n], 0, 0, 0);
        asm volatile("" ::: "memory");
        __builtin_amdgcn_s_barrier();
    }

    float bv[4];
#pragma unroll
    for (int n = 0; n < 4; ++n) bv[n] = bias[n0 + wc * 64 + n * 16 + lr];
#pragma unroll
    for (int m = 0; m < 4; ++m) {
#pragma unroll
        for (int r = 0; r < 4; ++r) {
            int orow = m0 + wr * 64 + m * 16 + kslot * 4 + r;
            size_t base = (size_t)orow * Ff + n0 + wc * 64 + lr;
#pragma unroll
            for (int n = 0; n < 4; ++n)
                h[base + n * 16] = f2bf(gelu_exact(acc[m][n][r] + bv[n]));
        }
    }
}

// Kernel 8: out[token] += w * (h @ w2t^T + b2)  (per expert; M=Cc, N=Dd, K=Ff)
// Split-K reverted (r4: -13%). Full K per block, single atomic epilogue.
__global__ __launch_bounds__(256) void moe_mfma_gemm2(
    const ushort_t* __restrict__ hbuf, const ushort_t* __restrict__ w2t,
    const float* __restrict__ b2, const int* __restrict__ srcOf,
    const float* __restrict__ wSlot, const int* __restrict__ counts,
    int chunk0, float* __restrict__ out) {
    int bx, by, le;
    swz_decode(Dd / 128, Cc / 128, bx, by, le);
    int e = chunk0 + le;
    const ushort_t* A = hbuf + (size_t)le * Cc * Ff;
    const ushort_t* Bt = w2t + (size_t)e * Dd * Ff;
    const float* bias = b2 + (size_t)e * Dd;
    const int* srcE = srcOf + (size_t)e * Cc;
    const float* wE = wSlot + (size_t)e * Cc;
    int count = counts[e];

    __shared__ short Al[2 * 4096];
    __shared__ short Bl[2 * 4096];

    int tid = threadIdx.x;
    int lane = tid & 63, wave = tid >> 6;
    int wr = wave >> 1, wc = wave & 1;
    int m0 = by * 128;
    int n0 = bx * 128;
    int kslot = lane >> 4, lr = lane & 15;
    int aoff = (kslot * 128 + wr * 64 + lr) * 8;
    int boff = (kslot * 128 + wc * 64 + lr) * 8;
    int wbase = (tid & 192) * 8;
    int row = tid & 127, ks0 = tid >> 7;

    const ushort_t* gA = A + (size_t)(m0 + row) * Ff + ks0 * 8;
    const ushort_t* gB = Bt + (size_t)(n0 + row) * Ff + ks0 * 8;

    f32x4 acc[4][4] = {};
    const int NT = Ff / 32;             // 64

    GSTAGE(gA, gB, Al, Bl, 0, 0, wbase);
    for (int t = 0; t < NT; ++t) {
        int cur = t & 1;
        if (t + 1 < NT) {
            GSTAGE(gA, gB, Al, Bl, cur ^ 1, t + 1, wbase);
            asm volatile("s_waitcnt vmcnt(4)" ::: "memory");
        } else {
            asm volatile("s_waitcnt vmcnt(0)" ::: "memory");
        }
        __builtin_amdgcn_s_barrier();
        asm volatile("" ::: "memory");
        bf16x8 a[4], b[4];
        int ab = cur * 4096 + aoff, bb = cur * 4096 + boff;
#pragma unroll
        for (int m = 0; m < 4; ++m) a[m] = *(const bf16x8*)&Al[ab + m * 128];
#pragma unroll
        for (int n = 0; n < 4; ++n) b[n] = *(const bf16x8*)&Bl[bb + n * 128];
#pragma unroll
        for (int m = 0; m < 4; ++m)
#pragma unroll
            for (int n = 0; n < 4; ++n)
                acc[m][n] = __builtin_amdgcn_mfma_f32_16x16x32_bf16(
                    a[m], b[n], acc[m][n], 0, 0, 0);
        asm volatile("" ::: "memory");
        __builtin_amdgcn_s_barrier();
    }

    float bv[4];
#pragma unroll
    for (int n = 0; n < 4; ++n) bv[n] = bias[n0 + wc * 64 + n * 16 + lr];
#pragma unroll
    for (int m = 0; m < 4; ++m) {
#pragma unroll
        for (int r = 0; r < 4; ++r) {
            int orow = m0 + wr * 64 + m * 16 + kslot * 4 + r;
            if (orow < count) {
                int token = srcE[orow];
                float wgt = wE[orow];
                float* op = out + (size_t)token * Dd + n0 + wc * 64 + lr;
#pragma unroll
                for (int n = 0; n < 4; ++n)
                    atomicAdd(&op[n * 16], wgt * (acc[m][n][r] + bv[n]));
            }
        }
    }
}

// ---------------------------------------------------------------------------
extern "C" void kernel_launch(void* const* d_in, const int* in_sizes, int n_in,
                              void* d_out, int out_size, void* d_ws, size_t ws_size,
                              hipStream_t stream) {
    const float* x      = (const float*)d_in[0];
    const float* gate_w = (const float*)d_in[1];
    const float* w1     = (const float*)d_in[2];
    const float* b1     = (const float*)d_in[3];
    const float* w2     = (const float*)d_in[4];
    const float* b2     = (const float*)d_in[5];
    float* out = (float*)d_out;

    char* p = (char*)d_ws;
    int*      flat_e       = (int*)p;       p += (size_t)NK * 4;
    float*    wArr         = (float*)p;     p += (size_t)NK * 4;
    int*      blockCounts  = (int*)p;       p += 256 * Ee * 4;
    int*      blockOffsets = (int*)p;       p += 256 * Ee * 4;
    int*      counts       = (int*)p;       p += 64 * 4;
    int*      srcOf        = (int*)p;       p += (size_t)Ee * Cc * 4;
    float*    wSlot        = (float*)p;     p += (size_t)Ee * Cc * 4;
    p = (char*)(((size_t)p + 255) & ~(size_t)255);
    ushort_t* w1t          = (ushort_t*)p;  p += (size_t)Ee * Dd * Ff * 2;
    ushort_t* w2t          = (ushort_t*)p;  p += (size_t)Ee * Ff * Dd * 2;
    size_t fixedEnd = (size_t)(p - (char*)d_ws);
    size_t avail = (ws_size > fixedEnd) ? ws_size - fixedEnd : 0;

    // per-expert chunk buffers: xg (Cc x Dd bf16) + h (Cc x Ff bf16)
    size_t perE = (size_t)Cc * Dd * 2 + (size_t)Cc * Ff * 2;
    int P = Ee;
    while (P > 1 && (size_t)P * perE > avail) P >>= 1;
    ushort_t* xg = (ushort_t*)((char*)d_ws + fixedEnd);
    ushort_t* hbuf = xg + (size_t)P * Cc * Dd;

    moe_gate_kernel<<<Nn / 4, 256, 0, stream>>>(x, gate_w, flat_e, wArr);
    moe_hist_kernel<<<NK / 256, 256, 0, stream>>>(flat_e, blockCounts);
    moe_scan_kernel<<<1, 64, 0, stream>>>(blockCounts, blockOffsets, counts);
    moe_scatter_kernel<<<NK / 256, 256, 0, stream>>>(flat_e, wArr, blockOffsets,
                                                     srcOf, wSlot);
    moe_transpose_kernel<<<dim3(Ff / 32, Dd / 32, Ee), 256, 0, stream>>>(
        w1, w1t, Dd, Ff);
    moe_transpose_kernel<<<dim3(Dd / 32, Ff / 32, Ee), 256, 0, stream>>>(
        w2, w2t, Ff, Dd);
    hipMemsetAsync(d_out, 0, (size_t)Nn * Dd * sizeof(float), stream);

    for (int c0 = 0; c0 < Ee; c0 += P) {
        moe_gather_kernel<<<P * Cc / 4, 256, 0, stream>>>(x, srcOf, counts, c0, xg);
        moe_mfma_gemm1<<<dim3(Ff / 128, Cc / 128, P), 256, 0, stream>>>(
            xg, w1t, b1, c0, hbuf);
        moe_mfma_gemm2<<<dim3(Dd / 128, Cc / 128, P), 256, 0, stream>>>(
            hbuf, w2t, b2, srcOf, wSlot, counts, c0, out);
    }
}